// Round 1
// baseline (257.590 us; speedup 1.0000x reference)
//
#include <hip/hip_runtime.h>

#define NODES 128
#define NFEAT 256
#define BATCH 512
#define KTOT  (NODES * NFEAT)   // 32768, stage-3 K
#define SPLIT 64                // stage-3 split-K factor
#define KCH   (KTOT / SPLIT)    // 512 per chunk

typedef __bf16 bf16_t;
typedef bf16_t bf16x8 __attribute__((ext_vector_type(8)));
typedef float  f32x4  __attribute__((ext_vector_type(4)));

#define BK   32
#define LDK  40      // padded LDS row length (bf16 elems): 80B, 16B-aligned rows
#define TILE 128

// ---- shared MFMA compute: 128x128 block tile, 4 waves, each wave 64x64 ----
// As/Bs are [128][LDK] bf16 tiles ([row][k]); pointers pre-offset to wave's 64 rows.
__device__ __forceinline__ void mfma_step(const bf16_t* As, const bf16_t* Bs,
                                          f32x4 acc[4][4], int lane) {
    const int l15 = lane & 15, q = lane >> 4;
    bf16x8 a[4], b[4];
#pragma unroll
    for (int i = 0; i < 4; i++)
        a[i] = *(const bf16x8*)(As + (i * 16 + l15) * LDK + q * 8);
#pragma unroll
    for (int j = 0; j < 4; j++)
        b[j] = *(const bf16x8*)(Bs + (j * 16 + l15) * LDK + q * 8);
#pragma unroll
    for (int i = 0; i < 4; i++)
#pragma unroll
        for (int j = 0; j < 4; j++)
            acc[i][j] = __builtin_amdgcn_mfma_f32_16x16x32_bf16(a[i], b[j], acc[i][j], 0, 0, 0);
}

// ---- stage 1: support = x[b] @ gcn_w, stored TRANSPOSED: supT[b][g][node] ----
__global__ __launch_bounds__(256)
void k_support(const float* __restrict__ x, const float* __restrict__ gcn_w,
               bf16_t* __restrict__ supT) {
    __shared__ __align__(16) bf16_t As[TILE * LDK];
    __shared__ __align__(16) bf16_t Bs[TILE * LDK];
    const int b   = blockIdx.x;          // batch; block's M-rows are nodes of b
    const int n0  = blockIdx.y * TILE;   // g offset (0 or 128)
    const int tid = threadIdx.x;
    const int lane = tid & 63, w = tid >> 6, wm = w & 1, wn = w >> 1;
    f32x4 acc[4][4] = {};
    const float* Arow = x + (size_t)b * NODES * NFEAT;

    for (int k0 = 0; k0 < NFEAT; k0 += BK) {
        // A tile: 128 nodes x 32 f (fp32 -> bf16), coalesced float4
#pragma unroll
        for (int i = 0; i < 4; i++) {
            int f = tid + i * 256;
            int r = f >> 3, c = f & 7;
            const float4 v = *(const float4*)(Arow + r * NFEAT + k0 + c * 4);
            bf16_t* d = As + r * LDK + c * 4;
            d[0] = (bf16_t)v.x; d[1] = (bf16_t)v.y; d[2] = (bf16_t)v.z; d[3] = (bf16_t)v.w;
        }
        // B tile: gcn_w[k][g] -> transpose-stage Bs[g][k]
#pragma unroll
        for (int i = 0; i < 4; i++) {
            int f = tid + i * 256;
            int k = f >> 5, c = f & 31;
            const float4 v = *(const float4*)(gcn_w + (size_t)(k0 + k) * NFEAT + n0 + c * 4);
            Bs[(c * 4 + 0) * LDK + k] = (bf16_t)v.x;
            Bs[(c * 4 + 1) * LDK + k] = (bf16_t)v.y;
            Bs[(c * 4 + 2) * LDK + k] = (bf16_t)v.z;
            Bs[(c * 4 + 3) * LDK + k] = (bf16_t)v.w;
        }
        __syncthreads();
        mfma_step(As + wm * 64 * LDK, Bs + wn * 64 * LDK, acc, lane);
        __syncthreads();
    }
    // epilogue: supT[b][g][node] (transposed store; L2 merges the 32KB region)
    const int l15 = lane & 15, q = lane >> 4;
    bf16_t* outb = supT + (size_t)b * NFEAT * NODES;
#pragma unroll
    for (int i = 0; i < 4; i++)
#pragma unroll
        for (int j = 0; j < 4; j++)
#pragma unroll
            for (int r = 0; r < 4; r++) {
                int node = wm * 64 + i * 16 + q * 4 + r;
                int g    = n0 + wn * 64 + j * 16 + l15;
                outb[(size_t)g * NODES + node] = (bf16_t)acc[i][j][r];
            }
}

// ---- stage 2: mid[b][n][g] = adj[b] @ support[b] + gcn_b ----
__global__ __launch_bounds__(256)
void k_mid(const float* __restrict__ adj, const bf16_t* __restrict__ supT,
           const float* __restrict__ gcn_b, bf16_t* __restrict__ mid) {
    __shared__ __align__(16) bf16_t As[TILE * LDK];
    __shared__ __align__(16) bf16_t Bs[TILE * LDK];
    const int b   = blockIdx.x;
    const int n0  = blockIdx.y * TILE;   // g offset
    const int tid = threadIdx.x;
    const int lane = tid & 63, w = tid >> 6, wm = w & 1, wn = w >> 1;
    f32x4 acc[4][4] = {};
    const float*  Arow = adj  + (size_t)b * NODES * NODES;
    const bf16_t* Brow = supT + (size_t)b * NFEAT * NODES;

    for (int k0 = 0; k0 < NODES; k0 += BK) {
        // A tile: adj 128 x 32 (fp32 -> bf16)
#pragma unroll
        for (int i = 0; i < 4; i++) {
            int f = tid + i * 256;
            int r = f >> 3, c = f & 7;
            const float4 v = *(const float4*)(Arow + r * NODES + k0 + c * 4);
            bf16_t* d = As + r * LDK + c * 4;
            d[0] = (bf16_t)v.x; d[1] = (bf16_t)v.y; d[2] = (bf16_t)v.z; d[3] = (bf16_t)v.w;
        }
        // B tile: supT[g][m] already K-contiguous, 16B vector copies
#pragma unroll
        for (int i = 0; i < 2; i++) {
            int f = tid + i * 256;
            int r = f >> 2, c = f & 3;
            bf16x8 v = *(const bf16x8*)(Brow + (size_t)(n0 + r) * NODES + k0 + c * 8);
            *(bf16x8*)(Bs + r * LDK + c * 8) = v;
        }
        __syncthreads();
        mfma_step(As + wm * 64 * LDK, Bs + wn * 64 * LDK, acc, lane);
        __syncthreads();
    }
    // epilogue: + gcn_b, store bf16 mid[b][node][g]
    const int l15 = lane & 15, q = lane >> 4;
    bf16_t* outb = mid + (size_t)b * NODES * NFEAT;
#pragma unroll
    for (int j = 0; j < 4; j++) {
        int g = n0 + wn * 64 + j * 16 + l15;
        float bias = gcn_b[g];
#pragma unroll
        for (int i = 0; i < 4; i++)
#pragma unroll
            for (int r = 0; r < 4; r++) {
                int node = wm * 64 + i * 16 + q * 4 + r;
                outb[(size_t)node * NFEAT + g] = (bf16_t)(acc[i][j][r] + bias);
            }
    }
}

// ---- stage 3: split-K GEMM: part[s][bt][o] = sum_{k in chunk} flat[bt][k]*fc_w[o][k]
__global__ __launch_bounds__(256)
void k_out(const bf16_t* __restrict__ flat, const float* __restrict__ fcw,
           float* __restrict__ part) {
    __shared__ __align__(16) bf16_t As[TILE * LDK];
    __shared__ __align__(16) bf16_t Bs[TILE * LDK];
    const int m0 = blockIdx.x * TILE;    // batch-row tile (4)
    const int n0 = blockIdx.y * TILE;    // output-col tile (2)
    const int s  = blockIdx.z;           // split index (64)
    const int kb = s * KCH;
    const int tid = threadIdx.x;
    const int lane = tid & 63, w = tid >> 6, wm = w & 1, wn = w >> 1;
    f32x4 acc[4][4] = {};

    for (int k0 = kb; k0 < kb + KCH; k0 += BK) {
        // A tile: flat (bf16) rows = batches, K-contiguous
#pragma unroll
        for (int i = 0; i < 2; i++) {
            int f = tid + i * 256;
            int r = f >> 2, c = f & 3;
            bf16x8 v = *(const bf16x8*)(flat + (size_t)(m0 + r) * KTOT + k0 + c * 8);
            *(bf16x8*)(As + r * LDK + c * 8) = v;
        }
        // B tile: fc_w rows = output neurons, K-contiguous (fp32 -> bf16)
#pragma unroll
        for (int i = 0; i < 4; i++) {
            int f = tid + i * 256;
            int r = f >> 3, c = f & 7;
            const float4 v = *(const float4*)(fcw + (size_t)(n0 + r) * KTOT + k0 + c * 4);
            bf16_t* d = Bs + r * LDK + c * 4;
            d[0] = (bf16_t)v.x; d[1] = (bf16_t)v.y; d[2] = (bf16_t)v.z; d[3] = (bf16_t)v.w;
        }
        __syncthreads();
        mfma_step(As + wm * 64 * LDK, Bs + wn * 64 * LDK, acc, lane);
        __syncthreads();
    }
    const int l15 = lane & 15, q = lane >> 4;
    float* pb = part + (size_t)s * BATCH * NFEAT;
#pragma unroll
    for (int i = 0; i < 4; i++)
#pragma unroll
        for (int j = 0; j < 4; j++)
#pragma unroll
            for (int r = 0; r < 4; r++) {
                int bt = m0 + wm * 64 + i * 16 + q * 4 + r;
                int o  = n0 + wn * 64 + j * 16 + l15;
                pb[(size_t)bt * NFEAT + o] = acc[i][j][r];
            }
}

// ---- stage 4: reduce partials + fc_b -> out slots 0,2; copy x[:,0,:] -> slot 1
__global__ __launch_bounds__(256)
void k_reduce(const float* __restrict__ part, const float* __restrict__ fc_b,
              const float* __restrict__ x, float* __restrict__ out) {
    const int g = blockIdx.x * 256 + threadIdx.x;   // 0..131071
    const int o = g & (NFEAT - 1), b = g >> 8;
    float s = fc_b[o];
#pragma unroll
    for (int i = 0; i < SPLIT; i++)
        s += part[(size_t)i * BATCH * NFEAT + g];
    out[g] = s;
    out[BATCH * NFEAT + g] = x[(size_t)b * NODES * NFEAT + o];  // x[b][0][o]
    out[2 * BATCH * NFEAT + g] = s;
}

extern "C" void kernel_launch(void* const* d_in, const int* in_sizes, int n_in,
                              void* d_out, int out_size, void* d_ws, size_t ws_size,
                              hipStream_t stream) {
    const float* x     = (const float*)d_in[0];
    const float* adj   = (const float*)d_in[1];
    const float* gcn_w = (const float*)d_in[2];
    const float* gcn_b = (const float*)d_in[3];
    const float* fc_w  = (const float*)d_in[4];
    const float* fc_b  = (const float*)d_in[5];
    float* out = (float*)d_out;

    // ws layout: [0, 32MB) supT (bf16), later aliased by part (fp32, same 32MB);
    //            [32MB, 64MB) mid/flat (bf16). Total 64MB.
    bf16_t* supT = (bf16_t*)d_ws;
    bf16_t* mid  = (bf16_t*)((char*)d_ws + (size_t)BATCH * NFEAT * NODES * 2);
    float*  part = (float*)d_ws;   // safe: k_out runs after k_mid (last supT reader)

    k_support<<<dim3(BATCH, 2), dim3(256), 0, stream>>>(x, gcn_w, supT);
    k_mid    <<<dim3(BATCH, 2), dim3(256), 0, stream>>>(adj, supT, gcn_b, mid);
    k_out    <<<dim3(4, 2, SPLIT), dim3(256), 0, stream>>>(mid, fc_w, part);
    k_reduce <<<dim3(BATCH), dim3(256), 0, stream>>>(part, fc_b, x, out);
}

// Round 2
// 221.156 us; speedup vs baseline: 1.1647x; 1.1647x over previous
//
#include <hip/hip_runtime.h>

#define NODES 128
#define NFEAT 256
#define BATCH 512
#define KTOT  (NODES * NFEAT)   // 32768, stage-3 K
#define SPLIT 32                // stage-3 split-K factor
#define KCH   (KTOT / SPLIT)    // 1024 per chunk

typedef __bf16 bf16_t;
typedef bf16_t bf16x8 __attribute__((ext_vector_type(8)));
typedef float  f32x4  __attribute__((ext_vector_type(4)));

#define BK   32
#define LDK  40      // padded LDS row (bf16): 80B rows, 16B-aligned
#define LDM  136     // Sb row stride (bf16): 272B rows, 16B-aligned
#define TILE 128

__device__ __forceinline__ bf16x8 cvt8(const float4 a, const float4 b) {
    bf16x8 t;
    t[0] = (bf16_t)a.x; t[1] = (bf16_t)a.y; t[2] = (bf16_t)a.z; t[3] = (bf16_t)a.w;
    t[4] = (bf16_t)b.x; t[5] = (bf16_t)b.y; t[6] = (bf16_t)b.z; t[7] = (bf16_t)b.w;
    return t;
}

// stage fp32 [rows x 32] -> LDS bf16 tile [rows][LDK], 16B writes (no conflicts)
// src row stride = srcld (floats). 256 threads stage 128x32.
__device__ __forceinline__ void stage_f32(const float* __restrict__ src, int srcld,
                                          int k0, bf16_t* __restrict__ dst, int tid) {
#pragma unroll
    for (int i = 0; i < 2; i++) {
        int f = tid + i * 256;          // 0..511
        int r = f >> 2, c = f & 3;      // row, 8-elem chunk
        const float4 v0 = *(const float4*)(src + (size_t)r * srcld + k0 + c * 8);
        const float4 v1 = *(const float4*)(src + (size_t)r * srcld + k0 + c * 8 + 4);
        *(bf16x8*)(dst + r * LDK + c * 8) = cvt8(v0, v1);
    }
}

// ---- 128x128 block tile MFMA: 4 waves, each 64x64; As/Bs [128][LDK] ----
__device__ __forceinline__ void mfma_step(const bf16_t* As, const bf16_t* Bs,
                                          f32x4 acc[4][4], int lane) {
    const int l15 = lane & 15, q = lane >> 4;
    bf16x8 a[4], b[4];
#pragma unroll
    for (int i = 0; i < 4; i++)
        a[i] = *(const bf16x8*)(As + (i * 16 + l15) * LDK + q * 8);
#pragma unroll
    for (int j = 0; j < 4; j++)
        b[j] = *(const bf16x8*)(Bs + (j * 16 + l15) * LDK + q * 8);
#pragma unroll
    for (int i = 0; i < 4; i++)
#pragma unroll
        for (int j = 0; j < 4; j++)
            acc[i][j] = __builtin_amdgcn_mfma_f32_16x16x32_bf16(a[i], b[j], acc[i][j], 0, 0, 0);
}

// ---- pre-transpose gcn_w[k][g] -> wT[g][k] bf16 (256x256, tiny) ----
__global__ __launch_bounds__(256)
void k_wt(const float* __restrict__ w, bf16_t* __restrict__ wT) {
    const int g0 = blockIdx.x * 4;      // 4 g-columns per block
    const int k  = threadIdx.x;
    const float4 v = *(const float4*)(w + (size_t)k * NFEAT + g0);
    wT[(size_t)(g0 + 0) * NFEAT + k] = (bf16_t)v.x;
    wT[(size_t)(g0 + 1) * NFEAT + k] = (bf16_t)v.y;
    wT[(size_t)(g0 + 2) * NFEAT + k] = (bf16_t)v.z;
    wT[(size_t)(g0 + 3) * NFEAT + k] = (bf16_t)v.w;
}

// ---- fused stages 1+2: per (g-tile, batch) block ----
// S = x[b] @ gcn_w[:, gtile]  (128x128, K=256) -> LDS Sb[g][m]
// mid[b][:, gtile] = adj[b] @ S + gcn_b        (128x128, K=128)
__global__ __launch_bounds__(256, 2)
void k_fused12(const float* __restrict__ x, const float* __restrict__ adj,
               const bf16_t* __restrict__ wT, const float* __restrict__ gcn_b,
               bf16_t* __restrict__ mid) {
    __shared__ __align__(16) bf16_t As[TILE * LDK];
    __shared__ __align__(16) bf16_t Bs[TILE * LDK];
    __shared__ __align__(16) bf16_t Sb[TILE * LDM];   // Sb[g_local][m], K(m)-contiguous
    const int n0  = blockIdx.x * TILE;   // g-tile offset (0 or 128)
    const int b   = blockIdx.y;
    const int tid = threadIdx.x;
    const int lane = tid & 63, w = tid >> 6, wm = w & 1, wn = w >> 1;
    const int l15 = lane & 15, q = lane >> 4;
    const float* xb   = x   + (size_t)b * NODES * NFEAT;
    const float* adjb = adj + (size_t)b * NODES * NODES;

    // ---- stage 1: S = x[b] @ wT[gtile]^T ----
    f32x4 acc[4][4] = {};
    for (int k0 = 0; k0 < NFEAT; k0 += BK) {
        stage_f32(xb, NFEAT, k0, As, tid);
        // Bs: wT rows n0..n0+127, cols k0..k0+31 — pure bf16x8 copies
#pragma unroll
        for (int i = 0; i < 2; i++) {
            int f = tid + i * 256;
            int r = f >> 2, c = f & 3;
            *(bf16x8*)(Bs + r * LDK + c * 8) =
                *(const bf16x8*)(wT + (size_t)(n0 + r) * NFEAT + k0 + c * 8);
        }
        __syncthreads();
        mfma_step(As + wm * 64 * LDK, Bs + wn * 64 * LDK, acc, lane);
        __syncthreads();
    }
    // S -> LDS Sb[g_local][m] (bf16)
#pragma unroll
    for (int i = 0; i < 4; i++)
#pragma unroll
        for (int j = 0; j < 4; j++)
#pragma unroll
            for (int r = 0; r < 4; r++) {
                int m = wm * 64 + i * 16 + q * 4 + r;
                int g = wn * 64 + j * 16 + l15;
                Sb[g * LDM + m] = (bf16_t)acc[i][j][r];
            }
    __syncthreads();

    // ---- stage 2: mid_tile = adj[b] @ S ----
    f32x4 acc2[4][4] = {};
    for (int k0 = 0; k0 < NODES; k0 += BK) {
        stage_f32(adjb, NODES, k0, As, tid);
        __syncthreads();
        bf16x8 a[4], bb[4];
#pragma unroll
        for (int i = 0; i < 4; i++)
            a[i] = *(const bf16x8*)(As + (wm * 64 + i * 16 + l15) * LDK + q * 8);
#pragma unroll
        for (int j = 0; j < 4; j++)
            bb[j] = *(const bf16x8*)(Sb + (wn * 64 + j * 16 + l15) * LDM + k0 + q * 8);
#pragma unroll
        for (int i = 0; i < 4; i++)
#pragma unroll
            for (int j = 0; j < 4; j++)
                acc2[i][j] = __builtin_amdgcn_mfma_f32_16x16x32_bf16(a[i], bb[j], acc2[i][j], 0, 0, 0);
        __syncthreads();
    }
    // epilogue: + gcn_b -> mid[b][node][g] bf16
    bf16_t* outb = mid + (size_t)b * NODES * NFEAT;
#pragma unroll
    for (int j = 0; j < 4; j++) {
        int g = n0 + wn * 64 + j * 16 + l15;
        float bias = gcn_b[g];
#pragma unroll
        for (int i = 0; i < 4; i++)
#pragma unroll
            for (int r = 0; r < 4; r++) {
                int node = wm * 64 + i * 16 + q * 4 + r;
                outb[(size_t)node * NFEAT + g] = (bf16_t)(acc2[i][j][r] + bias);
            }
    }
}

// ---- stage 3: split-K GEMM: part[s][bt][o] over K-chunk ----
__global__ __launch_bounds__(256)
void k_out(const bf16_t* __restrict__ flat, const float* __restrict__ fcw,
           float* __restrict__ part) {
    __shared__ __align__(16) bf16_t As[TILE * LDK];
    __shared__ __align__(16) bf16_t Bs[TILE * LDK];
    const int m0 = blockIdx.x * TILE;    // batch tile (4)
    const int n0 = blockIdx.y * TILE;    // out-neuron tile (2)
    const int s  = blockIdx.z;           // split index (32)
    const int kb = s * KCH;
    const int tid = threadIdx.x;
    const int lane = tid & 63, w = tid >> 6, wm = w & 1, wn = w >> 1;
    f32x4 acc[4][4] = {};

    for (int k0 = kb; k0 < kb + KCH; k0 += BK) {
        // A: flat bf16, K-contiguous — bf16x8 copies
#pragma unroll
        for (int i = 0; i < 2; i++) {
            int f = tid + i * 256;
            int r = f >> 2, c = f & 3;
            *(bf16x8*)(As + r * LDK + c * 8) =
                *(const bf16x8*)(flat + (size_t)(m0 + r) * KTOT + k0 + c * 8);
        }
        // B: fc_w fp32 -> bf16, 16B writes
        stage_f32(fcw + (size_t)n0 * KTOT, KTOT, k0, Bs, tid);
        __syncthreads();
        mfma_step(As + wm * 64 * LDK, Bs + wn * 64 * LDK, acc, lane);
        __syncthreads();
    }
    const int l15 = lane & 15, q = lane >> 4;
    float* pb = part + (size_t)s * BATCH * NFEAT;
#pragma unroll
    for (int i = 0; i < 4; i++)
#pragma unroll
        for (int j = 0; j < 4; j++)
#pragma unroll
            for (int r = 0; r < 4; r++) {
                int bt = m0 + wm * 64 + i * 16 + q * 4 + r;
                int o  = n0 + wn * 64 + j * 16 + l15;
                pb[(size_t)bt * NFEAT + o] = acc[i][j][r];
            }
}

// ---- stage 4: reduce partials + fc_b -> out slots 0,2; x[:,0,:] -> slot 1 ----
__global__ __launch_bounds__(256)
void k_reduce(const float* __restrict__ part, const float* __restrict__ fc_b,
              const float* __restrict__ x, float* __restrict__ out) {
    const int g = blockIdx.x * 256 + threadIdx.x;   // 0..131071
    const int o = g & (NFEAT - 1), b = g >> 8;
    float s = fc_b[o];
#pragma unroll
    for (int i = 0; i < SPLIT; i++)
        s += part[(size_t)i * BATCH * NFEAT + g];
    out[g] = s;
    out[BATCH * NFEAT + g] = x[(size_t)b * NODES * NFEAT + o];  // x[b][0][o]
    out[2 * BATCH * NFEAT + g] = s;
}

extern "C" void kernel_launch(void* const* d_in, const int* in_sizes, int n_in,
                              void* d_out, int out_size, void* d_ws, size_t ws_size,
                              hipStream_t stream) {
    const float* x     = (const float*)d_in[0];
    const float* adj   = (const float*)d_in[1];
    const float* gcn_w = (const float*)d_in[2];
    const float* gcn_b = (const float*)d_in[3];
    const float* fc_w  = (const float*)d_in[4];
    const float* fc_b  = (const float*)d_in[5];
    float* out = (float*)d_out;

    // ws layout: wT [0,128KB) | mid [128KB, +32MB) | part [33MB, +16MB)
    bf16_t* wT   = (bf16_t*)d_ws;
    bf16_t* mid  = (bf16_t*)((char*)d_ws + 131072);
    float*  part = (float*)((char*)d_ws + 131072 + (size_t)BATCH * NODES * NFEAT * 2);

    k_wt     <<<dim3(64), dim3(256), 0, stream>>>(gcn_w, wT);
    k_fused12<<<dim3(2, BATCH), dim3(256), 0, stream>>>(x, adj, wT, gcn_b, mid);
    k_out    <<<dim3(4, 2, SPLIT), dim3(256), 0, stream>>>(mid, fc_w, part);
    k_reduce <<<dim3(BATCH), dim3(256), 0, stream>>>(part, fc_b, x, out);
}